// Round 7
// baseline (13842.827 us; speedup 1.0000x reference)
//
#include <hip/hip_runtime.h>

#define H 4096
#define IN 64
#define OUTD 64
#define SEQ 4096
#define NBLK 256
#define ROWS_PER_BLK 16
#define NTHR 1024
#define SENT 0x7F7F7F7Fu   // 3.39e38f; tanh output in [-1,1] can never equal it

// ---- device-coherent (L2-bypassing, MALL-point) accessors -----------------
__device__ __forceinline__ uint4 cpoll1(const unsigned* p) {
    uint4 v;
    asm volatile("global_load_dwordx4 %0, %1, off sc0 sc1\n\t"
                 "s_waitcnt vmcnt(0)"
                 : "=&v"(v) : "v"(p) : "memory");
    return v;
}
__device__ __forceinline__ void cpoll4(const unsigned* p,
                                       uint4& a, uint4& b, uint4& c, uint4& d) {
    asm volatile(
        "global_load_dwordx4 %0, %4, off sc0 sc1\n\t"
        "global_load_dwordx4 %1, %4, off offset:16 sc0 sc1\n\t"
        "global_load_dwordx4 %2, %4, off offset:32 sc0 sc1\n\t"
        "global_load_dwordx4 %3, %4, off offset:48 sc0 sc1\n\t"
        "s_waitcnt vmcnt(0)"
        : "=&v"(a), "=&v"(b), "=&v"(c), "=&v"(d)
        : "v"(p) : "memory");
}
__device__ __forceinline__ void coherent_store_f32(float* p, float v) {
    asm volatile("global_store_dword %0, %1, off sc0 sc1"
                 :: "v"(p), "v"(v) : "memory");
}

__device__ __forceinline__ float row16_allreduce(float x) {
    x += __int_as_float(__builtin_amdgcn_update_dpp(0, __float_as_int(x), 0x128, 0xf, 0xf, false)); // row_ror:8
    x += __int_as_float(__builtin_amdgcn_update_dpp(0, __float_as_int(x), 0x124, 0xf, 0xf, false)); // row_ror:4
    x += __int_as_float(__builtin_amdgcn_update_dpp(0, __float_as_int(x), 0x122, 0xf, 0xf, false)); // row_ror:2
    x += __int_as_float(__builtin_amdgcn_update_dpp(0, __float_as_int(x), 0x121, 0xf, 0xf, false)); // row_ror:1
    return x;
}
__device__ __forceinline__ float quad4_allreduce(float x) {
    x += __int_as_float(__builtin_amdgcn_update_dpp(0, __float_as_int(x), 0xB1, 0xf, 0xf, false)); // perm 1,0,3,2
    x += __int_as_float(__builtin_amdgcn_update_dpp(0, __float_as_int(x), 0x4E, 0xf, 0xf, false)); // perm 2,3,0,1
    return x;
}

// tanh via exp + hw rcp: exact at saturation, ~1e-7 abs err mid-range
__device__ __forceinline__ float fast_tanh(float x) {
    float e = __expf(2.0f * x);
    return 1.0f - 2.0f * __builtin_amdgcn_rcpf(e + 1.0f);
}

__global__ __launch_bounds__(NTHR, 4)
void esn_scan(const float* __restrict__ inputs,   // (SEQ, IN)
              const float* __restrict__ W_in,     // (H, IN)
              const float* __restrict__ W_res,    // (H, H)
              float* __restrict__ out_states)     // (SEQ, H), sentinel-prefilled
{
    __shared__ alignas(16) float4 s_state4[H / 4];        // 1024 swizzled quads
    __shared__ alignas(16) float s_win[ROWS_PER_BLK][65]; // padded
    __shared__ alignas(16) float s_part[2][16][20];       // [parity][k(wave)][row+pad]
    __shared__ alignas(16) float s_u[IN];

    const int tid  = threadIdx.x;
    const int row0 = blockIdx.x * ROWS_PER_BLK;
    const int wave = tid >> 6;
    const int lane = tid & 63;
    const int rg   = lane >> 4;   // 0..3
    const int cgi  = lane & 15;   // 0..15
    const int col0 = wave * 256 + cgi * 16;

    for (int idx = tid; idx < ROWS_PER_BLK * IN; idx += NTHR)
        s_win[idx >> 6][idx & 63] = W_in[(size_t)row0 * IN + idx];

    float w[4][16];
#pragma unroll
    for (int j = 0; j < 4; ++j) {
        const float* src = W_res + (size_t)(row0 + 4 * rg + j) * H + col0;
#pragma unroll
        for (int q = 0; q < 4; ++q) {
            float4 v = *(const float4*)(src + 4 * q);
            w[j][4 * q + 0] = v.x; w[j][4 * q + 1] = v.y;
            w[j][4 * q + 2] = v.z; w[j][4 * q + 3] = v.w;
        }
    }

    for (int t = 0; t < SEQ; ++t) {
        const int par = t & 1;
        // ---- phase 1: only threads 0..255 poll (one per producer block).
        // Thread p probes quad0 of producer p's 64B line; on hit, reads the
        // full line with per-quad sentinel validation (partial-line guard),
        // then writes 4 swizzled LDS slots. Waves 4..15 park at B1 (silent
        // waiting -> no fabric contention during the publish window).
        if (tid < 256) {
            const int p     = tid;
            const int sbase = 64 * (p >> 4) + (p & 15);   // + 16*q per quad
            if (t == 0) {
#pragma unroll
                for (int q = 0; q < 4; ++q)
                    s_state4[sbase + 16 * q] = make_float4(0.f, 0.f, 0.f, 0.f);
            } else {
                const unsigned* src =
                    (const unsigned*)(out_states + (size_t)(t - 1) * H + 16 * p);
                // probe quad0 (16B) until the producer's line shows up
                for (;;) {
                    uint4 v = cpoll1(src);
                    if ((v.x != SENT) & (v.y != SENT) & (v.z != SENT) & (v.w != SENT))
                        break;
                    __builtin_amdgcn_s_sleep(1);
                }
                // pull the full 64B line; re-validate every quad (cheap; guards
                // against partial-line visibility of the 16-lane store)
                uint4 q0, q1, q2, q3;
                for (;;) {
                    cpoll4(src, q0, q1, q2, q3);
                    const bool bad =
                        (q0.x == SENT) | (q0.y == SENT) | (q0.z == SENT) | (q0.w == SENT) |
                        (q1.x == SENT) | (q1.y == SENT) | (q1.z == SENT) | (q1.w == SENT) |
                        (q2.x == SENT) | (q2.y == SENT) | (q2.z == SENT) | (q2.w == SENT) |
                        (q3.x == SENT) | (q3.y == SENT) | (q3.z == SENT) | (q3.w == SENT);
                    if (!bad) break;
                }
                float4 f0, f1, f2, f3;
                f0.x = __uint_as_float(q0.x); f0.y = __uint_as_float(q0.y);
                f0.z = __uint_as_float(q0.z); f0.w = __uint_as_float(q0.w);
                f1.x = __uint_as_float(q1.x); f1.y = __uint_as_float(q1.y);
                f1.z = __uint_as_float(q1.z); f1.w = __uint_as_float(q1.w);
                f2.x = __uint_as_float(q2.x); f2.y = __uint_as_float(q2.y);
                f2.z = __uint_as_float(q2.z); f2.w = __uint_as_float(q2.w);
                f3.x = __uint_as_float(q3.x); f3.y = __uint_as_float(q3.y);
                f3.z = __uint_as_float(q3.z); f3.w = __uint_as_float(q3.w);
                s_state4[sbase +  0] = f0;
                s_state4[sbase + 16] = f1;
                s_state4[sbase + 32] = f2;
                s_state4[sbase + 48] = f3;
            }
        } else if (tid < 272) {   // wave 4, lanes 0..15: stage u_t
            ((float4*)s_u)[tid - 256] =
                ((const float4*)(inputs + (size_t)t * IN))[tid - 256];
        }
        __syncthreads();   // B1: state + u staged (contention-free wait)

        // ---- phase 2: 4 rows x 16 cols FMA per lane, weights in regs
        float a0 = 0.f, a1 = 0.f, a2 = 0.f, a3 = 0.f;
#pragma unroll
        for (int q = 0; q < 4; ++q) {
            float4 sv = s_state4[wave * 64 + q * 16 + cgi];
            a0 = fmaf(w[0][4*q+0], sv.x, a0); a0 = fmaf(w[0][4*q+1], sv.y, a0);
            a0 = fmaf(w[0][4*q+2], sv.z, a0); a0 = fmaf(w[0][4*q+3], sv.w, a0);
            a1 = fmaf(w[1][4*q+0], sv.x, a1); a1 = fmaf(w[1][4*q+1], sv.y, a1);
            a1 = fmaf(w[1][4*q+2], sv.z, a1); a1 = fmaf(w[1][4*q+3], sv.w, a1);
            a2 = fmaf(w[2][4*q+0], sv.x, a2); a2 = fmaf(w[2][4*q+1], sv.y, a2);
            a2 = fmaf(w[2][4*q+2], sv.z, a2); a2 = fmaf(w[2][4*q+3], sv.w, a2);
            a3 = fmaf(w[3][4*q+0], sv.x, a3); a3 = fmaf(w[3][4*q+1], sv.y, a3);
            a3 = fmaf(w[3][4*q+2], sv.z, a3); a3 = fmaf(w[3][4*q+3], sv.w, a3);
        }
        a0 = row16_allreduce(a0);
        a1 = row16_allreduce(a1);
        a2 = row16_allreduce(a2);
        a3 = row16_allreduce(a3);
        if (cgi == 0) {
            float4 pv; pv.x = a0; pv.y = a1; pv.z = a2; pv.w = a3;
            *(float4*)&s_part[par][wave][4 * rg] = pv;
        }
        __syncthreads();   // B2: partials visible

        // ---- phase 3: wave0 finishes all 16 rows (no setprio — R6 lesson)
        if (wave == 0) {
            const int row = lane >> 2;  // 0..15
            const int j   = lane & 3;
            float v = s_part[par][4*j+0][row] + s_part[par][4*j+1][row]
                    + s_part[par][4*j+2][row] + s_part[par][4*j+3][row];
#pragma unroll
            for (int e = 0; e < 16; ++e)
                v = fmaf(s_win[row][16*j + e], s_u[16*j + e], v);
            v = quad4_allreduce(v);
            if (j == 0)
                coherent_store_f32(&out_states[(size_t)t * H + row0 + row],
                                   fast_tanh(v));
        }
        // no trailing barrier: consumers gate on the sentinel data; s_u/s_part
        // reuse is protected by B1/B2 of the next iteration (parity buffers).
    }
}

__device__ __forceinline__ float wave64_allreduce(float x) {
#pragma unroll
    for (int m = 1; m < 64; m <<= 1) x += __shfl_xor(x, m, 64);
    return x;
}

// One wave per timestep s; states row cached in 16 float4 regs across all 64 o.
__global__ __launch_bounds__(NTHR)
void esn_out(const float* __restrict__ inputs,
             const float* __restrict__ W_out,    // (OUTD, 4161) row-major
             const float* __restrict__ states,   // (SEQ, H)
             float* __restrict__ outputs)        // (SEQ, OUTD)
{
    const int wv   = threadIdx.x >> 6;
    const int lane = threadIdx.x & 63;
    const int s    = blockIdx.x * 16 + wv;
    const int K    = 1 + IN + H; // 4161

    const float4* st4 = (const float4*)(states + (size_t)s * H);
    float4 sq[16];
#pragma unroll
    for (int k = 0; k < 16; ++k)
        sq[k] = st4[64 * k + lane];
    float4 iq = make_float4(0.f, 0.f, 0.f, 0.f);
    if (lane < 16)
        iq = ((const float4*)(inputs + (size_t)s * IN))[lane];

    for (int o = 0; o < OUTD; ++o) {
        const float* wrow = W_out + (size_t)o * K;
        float acc = 0.f;
#pragma unroll
        for (int k = 0; k < 16; ++k) {
            float4 wq;   // wrow+65 is 4B-aligned only -> memcpy (safe dword loads)
            __builtin_memcpy(&wq, wrow + 65 + 4 * (64 * k + lane), 16);
            acc = fmaf(wq.x, sq[k].x, acc);
            acc = fmaf(wq.y, sq[k].y, acc);
            acc = fmaf(wq.z, sq[k].z, acc);
            acc = fmaf(wq.w, sq[k].w, acc);
        }
        if (lane < 16) {
            float4 wi;
            __builtin_memcpy(&wi, wrow + 1 + 4 * lane, 16);
            acc = fmaf(wi.x, iq.x, acc);
            acc = fmaf(wi.y, iq.y, acc);
            acc = fmaf(wi.z, iq.z, acc);
            acc = fmaf(wi.w, iq.w, acc);
            if (lane == 0) acc += wrow[0];   // bias
        }
        acc = wave64_allreduce(acc);
        if (lane == 0) outputs[(size_t)s * OUTD + o] = acc;
    }
}

extern "C" void kernel_launch(void* const* d_in, const int* in_sizes, int n_in,
                              void* d_out, int out_size, void* d_ws, size_t ws_size,
                              hipStream_t stream) {
    const float* inputs = (const float*)d_in[0];
    const float* W_in   = (const float*)d_in[1];
    const float* W_res  = (const float*)d_in[2];
    const float* W_out  = (const float*)d_in[3];

    float* outputs = (float*)d_out;                        // (SEQ, OUTD)
    float* states  = (float*)d_out + (size_t)SEQ * OUTD;   // (SEQ, H)

    // Sentinel-prefill states: one-hop data-poll handshake ground truth.
    hipMemsetAsync(states, 0x7F, (size_t)SEQ * H * sizeof(float), stream);

    void* args[] = { (void*)&inputs, (void*)&W_in, (void*)&W_res, (void*)&states };
    hipLaunchCooperativeKernel((void*)esn_scan, dim3(NBLK), dim3(NTHR),
                               args, 0, stream);

    esn_out<<<dim3(SEQ / 16), dim3(NTHR), 0, stream>>>(inputs, W_out, states, outputs);
}

// Round 10
// 11445.821 us; speedup vs baseline: 1.2094x; 1.2094x over previous
//
#include <hip/hip_runtime.h>

#define H 4096
#define IN 64
#define OUTD 64
#define SEQ 4096
#define NBLK 256
#define ROWS_PER_BLK 16
#define NTHR 1024
#define SENT 0x7F7F7F7Fu   // 3.39e38f; tanh output in [-1,1] can never equal it

// ---- device-coherent (L2-bypassing, MALL-point) accessors -----------------
__device__ __forceinline__ uint4 cpoll1(const unsigned* p) {
    uint4 v;
    asm volatile("global_load_dwordx4 %0, %1, off sc0 sc1\n\t"
                 "s_waitcnt vmcnt(0)"
                 : "=&v"(v) : "v"(p) : "memory");
    return v;
}
__device__ __forceinline__ void coherent_store_f32(float* p, float v) {
    asm volatile("global_store_dword %0, %1, off sc0 sc1"
                 :: "v"(p), "v"(v) : "memory");
}

__device__ __forceinline__ float row16_allreduce(float x) {
    // all-reduce across each 16-lane DPP row via rotate-and-add (VALU pipe)
    x += __int_as_float(__builtin_amdgcn_update_dpp(0, __float_as_int(x), 0x128, 0xf, 0xf, false)); // row_ror:8
    x += __int_as_float(__builtin_amdgcn_update_dpp(0, __float_as_int(x), 0x124, 0xf, 0xf, false)); // row_ror:4
    x += __int_as_float(__builtin_amdgcn_update_dpp(0, __float_as_int(x), 0x122, 0xf, 0xf, false)); // row_ror:2
    x += __int_as_float(__builtin_amdgcn_update_dpp(0, __float_as_int(x), 0x121, 0xf, 0xf, false)); // row_ror:1
    return x;
}

// tanh via exp + hw rcp: exact at saturation, ~1e-7 abs err mid-range
__device__ __forceinline__ float fast_tanh(float x) {
    float e = __expf(2.0f * x);
    return 1.0f - 2.0f * __builtin_amdgcn_rcpf(e + 1.0f);
}

__global__ __launch_bounds__(NTHR, 4)
void esn_scan(const float* __restrict__ inputs,   // (SEQ, IN)
              const float* __restrict__ W_in,     // (H, IN)
              const float* __restrict__ W_res,    // (H, H)
              float* __restrict__ out_states)     // (SEQ, H), sentinel-prefilled
{
    __shared__ alignas(16) float4 s_state4[H / 4];        // 1024 swizzled quads
    __shared__ alignas(16) float s_win[ROWS_PER_BLK][65]; // padded
    __shared__ alignas(16) float s_part[16][20];          // [k(wave)][row], padded
    __shared__ alignas(16) float s_u[2][IN];              // [parity][64]

    const int tid  = threadIdx.x;
    const int row0 = blockIdx.x * ROWS_PER_BLK;
    const int wave = tid >> 6;
    const int lane = tid & 63;
    const int rg   = lane >> 4;   // 0..3
    const int cgi  = lane & 15;   // 0..15
    const int col0 = wave * 256 + cgi * 16;

    // staging: thread polls ONE 16B quad: producer sp = tid>>2, sub-quad sq = tid&3
    // LDS slot = 64*(sp>>4) + 16*sq + (sp&15)  (wave-local region [64w, 64w+64))
    const int sp    = tid >> 2;
    const int sq    = tid & 3;
    const int sslot = 64 * (sp >> 4) + 16 * sq + (sp & 15);
    const int scol  = sp * 16 + sq * 4;

    for (int idx = tid; idx < ROWS_PER_BLK * IN; idx += NTHR)
        s_win[idx >> 6][idx & 63] = W_in[(size_t)row0 * IN + idx];

    float w[4][16];
#pragma unroll
    for (int j = 0; j < 4; ++j) {
        const float* src = W_res + (size_t)(row0 + 4 * rg + j) * H + col0;
#pragma unroll
        for (int q = 0; q < 4; ++q) {
            float4 v = *(const float4*)(src + 4 * q);
            w[j][4 * q + 0] = v.x; w[j][4 * q + 1] = v.y;
            w[j][4 * q + 2] = v.z; w[j][4 * q + 3] = v.w;
        }
    }

    for (int t = 0; t < SEQ; ++t) {
        const int par = t & 1;
        // ---- stage u_t (parity buffer: fixes latent cross-step race) and
        //      state row t-1 (one-hop sentinel poll, 16B per thread)
        if (tid < 16)
            ((float4*)s_u[par])[tid] = ((const float4*)(inputs + (size_t)t * IN))[tid];
        if (t == 0) {
            s_state4[sslot] = make_float4(0.f, 0.f, 0.f, 0.f);
        } else {
            const unsigned* p =
                (const unsigned*)(out_states + (size_t)(t - 1) * H + scol);
            uint4 v;
            for (;;) {
                v = cpoll1(p);
                if ((v.x != SENT) & (v.y != SENT) & (v.z != SENT) & (v.w != SENT))
                    break;
                __builtin_amdgcn_s_sleep(1);   // gentle backoff
            }
            float4 f;
            f.x = __uint_as_float(v.x); f.y = __uint_as_float(v.y);
            f.z = __uint_as_float(v.z); f.w = __uint_as_float(v.w);
            s_state4[sslot] = f;
        }
        __syncthreads();   // B1: state staged (contention-free wait)

        // ---- phase 2: 4 rows x 16 cols of FMA per lane, weights in VGPRs
        float a0 = 0.f, a1 = 0.f, a2 = 0.f, a3 = 0.f;
#pragma unroll
        for (int q = 0; q < 4; ++q) {
            float4 sv = s_state4[wave * 64 + q * 16 + cgi];
            a0 = fmaf(w[0][4*q+0], sv.x, a0); a0 = fmaf(w[0][4*q+1], sv.y, a0);
            a0 = fmaf(w[0][4*q+2], sv.z, a0); a0 = fmaf(w[0][4*q+3], sv.w, a0);
            a1 = fmaf(w[1][4*q+0], sv.x, a1); a1 = fmaf(w[1][4*q+1], sv.y, a1);
            a1 = fmaf(w[1][4*q+2], sv.z, a1); a1 = fmaf(w[1][4*q+3], sv.w, a1);
            a2 = fmaf(w[2][4*q+0], sv.x, a2); a2 = fmaf(w[2][4*q+1], sv.y, a2);
            a2 = fmaf(w[2][4*q+2], sv.z, a2); a2 = fmaf(w[2][4*q+3], sv.w, a2);
            a3 = fmaf(w[3][4*q+0], sv.x, a3); a3 = fmaf(w[3][4*q+1], sv.y, a3);
            a3 = fmaf(w[3][4*q+2], sv.z, a3); a3 = fmaf(w[3][4*q+3], sv.w, a3);
        }
        a0 = row16_allreduce(a0);
        a1 = row16_allreduce(a1);
        a2 = row16_allreduce(a2);
        a3 = row16_allreduce(a3);
        if (cgi == 0) {
            float4 pv; pv.x = a0; pv.y = a1; pv.z = a2; pv.w = a3;
            *(float4*)&s_part[wave][4 * rg] = pv;
        }
        __syncthreads();   // B2: partials visible

        // ---- phase 3: finish 16 rows (threads 0..255), fold W_in.u, tanh, publish
        if (tid < 256) {
            const int row = tid >> 4;
            const int k   = tid & 15;
            float v = s_part[k][row];
#pragma unroll
            for (int e = 0; e < 4; ++e)
                v = fmaf(s_win[row][4 * k + e], s_u[par][4 * k + e], v);
            v = row16_allreduce(v);
            if (k == 0)
                coherent_store_f32(&out_states[(size_t)t * H + row0 + row],
                                   fast_tanh(v));
        }
        // no trailing barrier: consumers gate on the sentinel data itself;
        // s_part reuse is protected by B2(t)/B1(t+1); s_u by parity.
    }
}

__device__ __forceinline__ float wave64_allreduce(float x) {
#pragma unroll
    for (int m = 1; m < 64; m <<= 1) x += __shfl_xor(x, m, 64);
    return x;
}

// One wave per timestep s; states row cached in 16 float4 regs across all 64 o.
__global__ __launch_bounds__(NTHR)
void esn_out(const float* __restrict__ inputs,
             const float* __restrict__ W_out,    // (OUTD, 4161) row-major
             const float* __restrict__ states,   // (SEQ, H)
             float* __restrict__ outputs)        // (SEQ, OUTD)
{
    const int wv   = threadIdx.x >> 6;
    const int lane = threadIdx.x & 63;
    const int s    = blockIdx.x * 16 + wv;
    const int K    = 1 + IN + H; // 4161

    const float4* st4 = (const float4*)(states + (size_t)s * H);
    float4 sq[16];
#pragma unroll
    for (int k = 0; k < 16; ++k)
        sq[k] = st4[64 * k + lane];
    float4 iq = make_float4(0.f, 0.f, 0.f, 0.f);
    if (lane < 16)
        iq = ((const float4*)(inputs + (size_t)s * IN))[lane];

    for (int o = 0; o < OUTD; ++o) {
        const float* wrow = W_out + (size_t)o * K;
        float acc = 0.f;
#pragma unroll
        for (int k = 0; k < 16; ++k) {
            float4 wq;   // wrow+65 is only 4B-aligned -> memcpy (dword loads)
            __builtin_memcpy(&wq, wrow + 65 + 4 * (64 * k + lane), 16);
            acc = fmaf(wq.x, sq[k].x, acc);
            acc = fmaf(wq.y, sq[k].y, acc);
            acc = fmaf(wq.z, sq[k].z, acc);
            acc = fmaf(wq.w, sq[k].w, acc);
        }
        if (lane < 16) {
            float4 wi;
            __builtin_memcpy(&wi, wrow + 1 + 4 * lane, 16);
            acc = fmaf(wi.x, iq.x, acc);
            acc = fmaf(wi.y, iq.y, acc);
            acc = fmaf(wi.z, iq.z, acc);
            acc = fmaf(wi.w, iq.w, acc);
            if (lane == 0) acc += wrow[0];   // bias
        }
        acc = wave64_allreduce(acc);
        if (lane == 0) outputs[(size_t)s * OUTD + o] = acc;
    }
}

extern "C" void kernel_launch(void* const* d_in, const int* in_sizes, int n_in,
                              void* d_out, int out_size, void* d_ws, size_t ws_size,
                              hipStream_t stream) {
    const float* inputs = (const float*)d_in[0];
    const float* W_in   = (const float*)d_in[1];
    const float* W_res  = (const float*)d_in[2];
    const float* W_out  = (const float*)d_in[3];

    float* outputs = (float*)d_out;                        // (SEQ, OUTD)
    float* states  = (float*)d_out + (size_t)SEQ * OUTD;   // (SEQ, H)

    // Sentinel-prefill states: one-hop data-poll handshake ground truth.
    (void)hipMemsetAsync(states, 0x7F, (size_t)SEQ * H * sizeof(float), stream);

    void* args[] = { (void*)&inputs, (void*)&W_in, (void*)&W_res, (void*)&states };
    (void)hipLaunchCooperativeKernel((void*)esn_scan, dim3(NBLK), dim3(NTHR),
                                     args, 0, stream);

    esn_out<<<dim3(SEQ / 16), dim3(NTHR), 0, stream>>>(inputs, W_out, states, outputs);
}

// Round 11
// 9472.518 us; speedup vs baseline: 1.4614x; 1.2083x over previous
//
#include <hip/hip_runtime.h>

#define H 4096
#define IN 64
#define OUTD 64
#define SEQ 4096
#define NBLK 256
#define ROWS_PER_BLK 16
#define NTHR 1024
#define SENT 0x7F7F7F7Fu   // 3.39e38f; tanh output in [-1,1] can never equal it

// ---- device-coherent (L2-bypassing, MALL-point) accessors -----------------
__device__ __forceinline__ uint4 cpoll1(const unsigned* p) {
    uint4 v;
    asm volatile("global_load_dwordx4 %0, %1, off sc0 sc1\n\t"
                 "s_waitcnt vmcnt(0)"
                 : "=&v"(v) : "v"(p) : "memory");
    return v;
}
__device__ __forceinline__ void coherent_store_f32(float* p, float v) {
    asm volatile("global_store_dword %0, %1, off sc0 sc1"
                 :: "v"(p), "v"(v) : "memory");
}

__device__ __forceinline__ float row16_allreduce(float x) {
    x += __int_as_float(__builtin_amdgcn_update_dpp(0, __float_as_int(x), 0x128, 0xf, 0xf, false)); // row_ror:8
    x += __int_as_float(__builtin_amdgcn_update_dpp(0, __float_as_int(x), 0x124, 0xf, 0xf, false)); // row_ror:4
    x += __int_as_float(__builtin_amdgcn_update_dpp(0, __float_as_int(x), 0x122, 0xf, 0xf, false)); // row_ror:2
    x += __int_as_float(__builtin_amdgcn_update_dpp(0, __float_as_int(x), 0x121, 0xf, 0xf, false)); // row_ror:1
    return x;
}
__device__ __forceinline__ float quad4_allreduce(float x) {
    x += __int_as_float(__builtin_amdgcn_update_dpp(0, __float_as_int(x), 0xB1, 0xf, 0xf, false)); // perm 1,0,3,2
    x += __int_as_float(__builtin_amdgcn_update_dpp(0, __float_as_int(x), 0x4E, 0xf, 0xf, false)); // perm 2,3,0,1
    return x;
}

__global__ __launch_bounds__(NTHR, 4)
void esn_scan(const float* __restrict__ inputs,   // (SEQ, IN)
              const float* __restrict__ W_in,     // (H, IN)
              const float* __restrict__ W_res,    // (H, H)
              float* __restrict__ out_states)     // (SEQ, H), sentinel-prefilled
{
    __shared__ alignas(16) float4 s_state4[H / 4];        // 1024 swizzled quads
    __shared__ alignas(16) float s_win[ROWS_PER_BLK][65]; // padded
    __shared__ alignas(16) float s_part[16][20];          // [k(wave)][row], padded
    __shared__ alignas(16) float s_u[IN];

    const int tid  = threadIdx.x;
    const int row0 = blockIdx.x * ROWS_PER_BLK;
    const int wave = tid >> 6;
    const int lane = tid & 63;
    const int rg   = lane >> 4;   // 0..3
    const int cgi  = lane & 15;   // 0..15
    const int col0 = wave * 256 + cgi * 16;

    // staging: thread polls ONE 16B quad: producer sp = tid>>2, sub-quad sq = tid&3
    // LDS slot = 64*(sp>>4) + 16*sq + (sp&15)
    const int sp    = tid >> 2;
    const int sq    = tid & 3;
    const int sslot = 64 * (sp >> 4) + 16 * sq + (sp & 15);
    const int scol  = sp * 16 + sq * 4;

    for (int idx = tid; idx < ROWS_PER_BLK * IN; idx += NTHR)
        s_win[idx >> 6][idx & 63] = W_in[(size_t)row0 * IN + idx];

    float w[4][16];
#pragma unroll
    for (int j = 0; j < 4; ++j) {
        const float* src = W_res + (size_t)(row0 + 4 * rg + j) * H + col0;
#pragma unroll
        for (int q = 0; q < 4; ++q) {
            float4 v = *(const float4*)(src + 4 * q);
            w[j][4 * q + 0] = v.x; w[j][4 * q + 1] = v.y;
            w[j][4 * q + 2] = v.z; w[j][4 * q + 3] = v.w;
        }
    }

    for (int t = 0; t < SEQ; ++t) {
        // ---- stage u_t (wave0 lanes 0..15: written & read only by wave0 ->
        //      program-order safe) and state row t-1 (one-hop 16B poll/thread)
        if (tid < 16)
            ((float4*)s_u)[tid] = ((const float4*)(inputs + (size_t)t * IN))[tid];
        if (t == 0) {
            s_state4[sslot] = make_float4(0.f, 0.f, 0.f, 0.f);
        } else {
            const unsigned* p =
                (const unsigned*)(out_states + (size_t)(t - 1) * H + scol);
            uint4 v;
            for (;;) {
                v = cpoll1(p);
                if ((v.x != SENT) & (v.y != SENT) & (v.z != SENT) & (v.w != SENT))
                    break;
                __builtin_amdgcn_s_sleep(1);   // gentle backoff
            }
            float4 f;
            f.x = __uint_as_float(v.x); f.y = __uint_as_float(v.y);
            f.z = __uint_as_float(v.z); f.w = __uint_as_float(v.w);
            s_state4[sslot] = f;
        }
        __syncthreads();   // B1: state staged (also protects s_part reuse)

        // ---- phase 2: 4 rows x 16 cols of FMA per lane, weights in VGPRs
        float a0 = 0.f, a1 = 0.f, a2 = 0.f, a3 = 0.f;
#pragma unroll
        for (int q = 0; q < 4; ++q) {
            float4 sv = s_state4[wave * 64 + q * 16 + cgi];
            a0 = fmaf(w[0][4*q+0], sv.x, a0); a0 = fmaf(w[0][4*q+1], sv.y, a0);
            a0 = fmaf(w[0][4*q+2], sv.z, a0); a0 = fmaf(w[0][4*q+3], sv.w, a0);
            a1 = fmaf(w[1][4*q+0], sv.x, a1); a1 = fmaf(w[1][4*q+1], sv.y, a1);
            a1 = fmaf(w[1][4*q+2], sv.z, a1); a1 = fmaf(w[1][4*q+3], sv.w, a1);
            a2 = fmaf(w[2][4*q+0], sv.x, a2); a2 = fmaf(w[2][4*q+1], sv.y, a2);
            a2 = fmaf(w[2][4*q+2], sv.z, a2); a2 = fmaf(w[2][4*q+3], sv.w, a2);
            a3 = fmaf(w[3][4*q+0], sv.x, a3); a3 = fmaf(w[3][4*q+1], sv.y, a3);
            a3 = fmaf(w[3][4*q+2], sv.z, a3); a3 = fmaf(w[3][4*q+3], sv.w, a3);
        }
        a0 = row16_allreduce(a0);
        a1 = row16_allreduce(a1);
        a2 = row16_allreduce(a2);
        a3 = row16_allreduce(a3);
        if (cgi == 0) {
            float4 pv; pv.x = a0; pv.y = a1; pv.z = a2; pv.w = a3;
            *(float4*)&s_part[wave][4 * rg] = pv;
        }
        __syncthreads();   // B2: partials visible

        // ---- phase 3: wave0 alone finishes all 16 rows; ONE coalesced 64B
        // publish (16 lanes, one store instruction -> minimal publish skew).
        // Waves 1..15 fall through to next step's polls.
        if (wave == 0) {
            const int row = lane >> 2;  // 0..15
            const int j   = lane & 3;   // partial group
            float v = s_part[4*j+0][row] + s_part[4*j+1][row]
                    + s_part[4*j+2][row] + s_part[4*j+3][row];
#pragma unroll
            for (int e = 0; e < 16; ++e)
                v = fmaf(s_win[row][16*j + e], s_u[16*j + e], v);
            v = quad4_allreduce(v);
            if (j == 0)
                coherent_store_f32(&out_states[(size_t)t * H + row0 + row],
                                   tanhf(v));
        }
        // no trailing barrier: consumers gate on the sentinel data itself.
    }
}

__device__ __forceinline__ float wave64_allreduce(float x) {
#pragma unroll
    for (int m = 1; m < 64; m <<= 1) x += __shfl_xor(x, m, 64);
    return x;
}

// One wave per timestep s; states row cached in 16 float4 regs across all 64 o.
__global__ __launch_bounds__(NTHR)
void esn_out(const float* __restrict__ inputs,
             const float* __restrict__ W_out,    // (OUTD, 4161) row-major
             const float* __restrict__ states,   // (SEQ, H)
             float* __restrict__ outputs)        // (SEQ, OUTD)
{
    const int wv   = threadIdx.x >> 6;
    const int lane = threadIdx.x & 63;
    const int s    = blockIdx.x * 16 + wv;
    const int K    = 1 + IN + H; // 4161

    const float4* st4 = (const float4*)(states + (size_t)s * H);
    float4 sq[16];
#pragma unroll
    for (int k = 0; k < 16; ++k)
        sq[k] = st4[64 * k + lane];
    float4 iq = make_float4(0.f, 0.f, 0.f, 0.f);
    if (lane < 16)
        iq = ((const float4*)(inputs + (size_t)s * IN))[lane];

    for (int o = 0; o < OUTD; ++o) {
        const float* wrow = W_out + (size_t)o * K;
        float acc = 0.f;
#pragma unroll
        for (int k = 0; k < 16; ++k) {
            float4 wq;   // wrow+65 is only 4B-aligned -> memcpy (dword loads)
            __builtin_memcpy(&wq, wrow + 65 + 4 * (64 * k + lane), 16);
            acc = fmaf(wq.x, sq[k].x, acc);
            acc = fmaf(wq.y, sq[k].y, acc);
            acc = fmaf(wq.z, sq[k].z, acc);
            acc = fmaf(wq.w, sq[k].w, acc);
        }
        if (lane < 16) {
            float4 wi;
            __builtin_memcpy(&wi, wrow + 1 + 4 * lane, 16);
            acc = fmaf(wi.x, iq.x, acc);
            acc = fmaf(wi.y, iq.y, acc);
            acc = fmaf(wi.z, iq.z, acc);
            acc = fmaf(wi.w, iq.w, acc);
            if (lane == 0) acc += wrow[0];   // bias
        }
        acc = wave64_allreduce(acc);
        if (lane == 0) outputs[(size_t)s * OUTD + o] = acc;
    }
}

extern "C" void kernel_launch(void* const* d_in, const int* in_sizes, int n_in,
                              void* d_out, int out_size, void* d_ws, size_t ws_size,
                              hipStream_t stream) {
    const float* inputs = (const float*)d_in[0];
    const float* W_in   = (const float*)d_in[1];
    const float* W_res  = (const float*)d_in[2];
    const float* W_out  = (const float*)d_in[3];

    float* outputs = (float*)d_out;                        // (SEQ, OUTD)
    float* states  = (float*)d_out + (size_t)SEQ * OUTD;   // (SEQ, H)

    // Sentinel-prefill states: one-hop data-poll handshake ground truth.
    (void)hipMemsetAsync(states, 0x7F, (size_t)SEQ * H * sizeof(float), stream);

    void* args[] = { (void*)&inputs, (void*)&W_in, (void*)&W_res, (void*)&states };
    (void)hipLaunchCooperativeKernel((void*)esn_scan, dim3(NBLK), dim3(NTHR),
                                     args, 0, stream);

    esn_out<<<dim3(SEQ / 16), dim3(NTHR), 0, stream>>>(inputs, W_out, states, outputs);
}

// Round 12
// 8442.213 us; speedup vs baseline: 1.6397x; 1.1220x over previous
//
#include <hip/hip_runtime.h>

#define H 4096
#define IN 64
#define OUTD 64
#define SEQ 4096
#define NBLK 256
#define ROWS_PER_BLK 16
#define NTHR 1024
#define SENT 0x7F7F7F7Fu   // 3.39e38f; tanh output in [-1,1] can never equal it

// ---- device-coherent (L2-bypassing, MALL-point) accessors -----------------
__device__ __forceinline__ uint4 cpoll1(const unsigned* p) {
    uint4 v;
    asm volatile("global_load_dwordx4 %0, %1, off sc0 sc1\n\t"
                 "s_waitcnt vmcnt(0)"
                 : "=&v"(v) : "v"(p) : "memory");
    return v;
}
__device__ __forceinline__ void coherent_store_f32(float* p, float v) {
    asm volatile("global_store_dword %0, %1, off sc0 sc1"
                 :: "v"(p), "v"(v) : "memory");
}

__device__ __forceinline__ float row16_allreduce(float x) {
    x += __int_as_float(__builtin_amdgcn_update_dpp(0, __float_as_int(x), 0x128, 0xf, 0xf, false)); // row_ror:8
    x += __int_as_float(__builtin_amdgcn_update_dpp(0, __float_as_int(x), 0x124, 0xf, 0xf, false)); // row_ror:4
    x += __int_as_float(__builtin_amdgcn_update_dpp(0, __float_as_int(x), 0x122, 0xf, 0xf, false)); // row_ror:2
    x += __int_as_float(__builtin_amdgcn_update_dpp(0, __float_as_int(x), 0x121, 0xf, 0xf, false)); // row_ror:1
    return x;
}
__device__ __forceinline__ float quad4_allreduce(float x) {
    x += __int_as_float(__builtin_amdgcn_update_dpp(0, __float_as_int(x), 0xB1, 0xf, 0xf, false)); // perm 1,0,3,2
    x += __int_as_float(__builtin_amdgcn_update_dpp(0, __float_as_int(x), 0x4E, 0xf, 0xf, false)); // perm 2,3,0,1
    return x;
}

__global__ __launch_bounds__(NTHR, 4)
void esn_scan(const float* __restrict__ inputs,   // (SEQ, IN)
              const float* __restrict__ W_in,     // (H, IN)
              const float* __restrict__ W_res,    // (H, H)
              float* __restrict__ out_states)     // (SEQ, H), sentinel-prefilled
{
    __shared__ alignas(16) float4 s_state4[H / 4];        // 1024 swizzled quads
    __shared__ alignas(16) float s_win[ROWS_PER_BLK][65]; // padded
    __shared__ alignas(16) float s_part[16][20];          // [k(wave)][row], padded
    __shared__ alignas(16) float s_u[IN];

    const int tid  = threadIdx.x;
    const int row0 = blockIdx.x * ROWS_PER_BLK;
    const int wave = tid >> 6;
    const int lane = tid & 63;
    const int rg   = lane >> 4;   // 0..3
    const int cgi  = lane & 15;   // 0..15
    const int col0 = wave * 256 + cgi * 16;

    // staging: thread polls ONE 16B quad: producer sp = tid>>2, sub-quad sq = tid&3
    // LDS slot = 64*(sp>>4) + 16*sq + (sp&15)
    const int sp    = tid >> 2;
    const int sq    = tid & 3;
    const int sslot = 64 * (sp >> 4) + 16 * sq + (sp & 15);
    const int scol  = sp * 16 + sq * 4;

    for (int idx = tid; idx < ROWS_PER_BLK * IN; idx += NTHR)
        s_win[idx >> 6][idx & 63] = W_in[(size_t)row0 * IN + idx];

    float w[4][16];
#pragma unroll
    for (int j = 0; j < 4; ++j) {
        const float* src = W_res + (size_t)(row0 + 4 * rg + j) * H + col0;
#pragma unroll
        for (int q = 0; q < 4; ++q) {
            float4 v = *(const float4*)(src + 4 * q);
            w[j][4 * q + 0] = v.x; w[j][4 * q + 1] = v.y;
            w[j][4 * q + 2] = v.z; w[j][4 * q + 3] = v.w;
        }
    }

    for (int t = 0; t < SEQ; ++t) {
        // ---- stage u_t (wave0-local) and state row t-1 (one-hop 16B poll)
        if (tid < 16)
            ((float4*)s_u)[tid] = ((const float4*)(inputs + (size_t)t * IN))[tid];
        if (t == 0) {
            s_state4[sslot] = make_float4(0.f, 0.f, 0.f, 0.f);
        } else {
            const unsigned* p =
                (const unsigned*)(out_states + (size_t)(t - 1) * H + scol);
            // calibrated backoff: immediate first probe (late-block fast path);
            // on miss, ~512cyc sleep skips the publish dead-window, then ~128cyc
            // between retries. Cuts MALL poll-request contention ~4x vs spin.
            uint4 v = cpoll1(p);
            if ((v.x == SENT) | (v.y == SENT) | (v.z == SENT) | (v.w == SENT)) {
                __builtin_amdgcn_s_sleep(8);
                for (;;) {
                    v = cpoll1(p);
                    if ((v.x != SENT) & (v.y != SENT) &
                        (v.z != SENT) & (v.w != SENT))
                        break;
                    __builtin_amdgcn_s_sleep(2);
                }
            }
            float4 f;
            f.x = __uint_as_float(v.x); f.y = __uint_as_float(v.y);
            f.z = __uint_as_float(v.z); f.w = __uint_as_float(v.w);
            s_state4[sslot] = f;
        }
        __syncthreads();   // B1: state staged (also protects s_part reuse)

        // ---- phase 2: 4 rows x 16 cols of FMA per lane, weights in VGPRs
        float a0 = 0.f, a1 = 0.f, a2 = 0.f, a3 = 0.f;
#pragma unroll
        for (int q = 0; q < 4; ++q) {
            float4 sv = s_state4[wave * 64 + q * 16 + cgi];
            a0 = fmaf(w[0][4*q+0], sv.x, a0); a0 = fmaf(w[0][4*q+1], sv.y, a0);
            a0 = fmaf(w[0][4*q+2], sv.z, a0); a0 = fmaf(w[0][4*q+3], sv.w, a0);
            a1 = fmaf(w[1][4*q+0], sv.x, a1); a1 = fmaf(w[1][4*q+1], sv.y, a1);
            a1 = fmaf(w[1][4*q+2], sv.z, a1); a1 = fmaf(w[1][4*q+3], sv.w, a1);
            a2 = fmaf(w[2][4*q+0], sv.x, a2); a2 = fmaf(w[2][4*q+1], sv.y, a2);
            a2 = fmaf(w[2][4*q+2], sv.z, a2); a2 = fmaf(w[2][4*q+3], sv.w, a2);
            a3 = fmaf(w[3][4*q+0], sv.x, a3); a3 = fmaf(w[3][4*q+1], sv.y, a3);
            a3 = fmaf(w[3][4*q+2], sv.z, a3); a3 = fmaf(w[3][4*q+3], sv.w, a3);
        }
        a0 = row16_allreduce(a0);
        a1 = row16_allreduce(a1);
        a2 = row16_allreduce(a2);
        a3 = row16_allreduce(a3);
        if (cgi == 0) {
            float4 pv; pv.x = a0; pv.y = a1; pv.z = a2; pv.w = a3;
            *(float4*)&s_part[wave][4 * rg] = pv;
        }
        __syncthreads();   // B2: partials visible

        // ---- phase 3: wave0 alone finishes all 16 rows; ONE coalesced 64B
        // publish (16 lanes, one store instruction -> minimal publish skew).
        if (wave == 0) {
            const int row = lane >> 2;  // 0..15
            const int j   = lane & 3;   // partial group
            float v = s_part[4*j+0][row] + s_part[4*j+1][row]
                    + s_part[4*j+2][row] + s_part[4*j+3][row];
#pragma unroll
            for (int e = 0; e < 16; ++e)
                v = fmaf(s_win[row][16*j + e], s_u[16*j + e], v);
            v = quad4_allreduce(v);
            if (j == 0)
                coherent_store_f32(&out_states[(size_t)t * H + row0 + row],
                                   tanhf(v));
        }
        // no trailing barrier: consumers gate on the sentinel data itself.
    }
}

__device__ __forceinline__ float wave64_allreduce(float x) {
#pragma unroll
    for (int m = 1; m < 64; m <<= 1) x += __shfl_xor(x, m, 64);
    return x;
}

// One wave per timestep s; states row cached in 16 float4 regs across all 64 o.
__global__ __launch_bounds__(NTHR)
void esn_out(const float* __restrict__ inputs,
             const float* __restrict__ W_out,    // (OUTD, 4161) row-major
             const float* __restrict__ states,   // (SEQ, H)
             float* __restrict__ outputs)        // (SEQ, OUTD)
{
    const int wv   = threadIdx.x >> 6;
    const int lane = threadIdx.x & 63;
    const int s    = blockIdx.x * 16 + wv;
    const int K    = 1 + IN + H; // 4161

    const float4* st4 = (const float4*)(states + (size_t)s * H);
    float4 sq[16];
#pragma unroll
    for (int k = 0; k < 16; ++k)
        sq[k] = st4[64 * k + lane];
    float4 iq = make_float4(0.f, 0.f, 0.f, 0.f);
    if (lane < 16)
        iq = ((const float4*)(inputs + (size_t)s * IN))[lane];

    for (int o = 0; o < OUTD; ++o) {
        const float* wrow = W_out + (size_t)o * K;
        float acc = 0.f;
#pragma unroll
        for (int k = 0; k < 16; ++k) {
            float4 wq;   // wrow+65 is only 4B-aligned -> memcpy (dword loads)
            __builtin_memcpy(&wq, wrow + 65 + 4 * (64 * k + lane), 16);
            acc = fmaf(wq.x, sq[k].x, acc);
            acc = fmaf(wq.y, sq[k].y, acc);
            acc = fmaf(wq.z, sq[k].z, acc);
            acc = fmaf(wq.w, sq[k].w, acc);
        }
        if (lane < 16) {
            float4 wi;
            __builtin_memcpy(&wi, wrow + 1 + 4 * lane, 16);
            acc = fmaf(wi.x, iq.x, acc);
            acc = fmaf(wi.y, iq.y, acc);
            acc = fmaf(wi.z, iq.z, acc);
            acc = fmaf(wi.w, iq.w, acc);
            if (lane == 0) acc += wrow[0];   // bias
        }
        acc = wave64_allreduce(acc);
        if (lane == 0) outputs[(size_t)s * OUTD + o] = acc;
    }
}

extern "C" void kernel_launch(void* const* d_in, const int* in_sizes, int n_in,
                              void* d_out, int out_size, void* d_ws, size_t ws_size,
                              hipStream_t stream) {
    const float* inputs = (const float*)d_in[0];
    const float* W_in   = (const float*)d_in[1];
    const float* W_res  = (const float*)d_in[2];
    const float* W_out  = (const float*)d_in[3];

    float* outputs = (float*)d_out;                        // (SEQ, OUTD)
    float* states  = (float*)d_out + (size_t)SEQ * OUTD;   // (SEQ, H)

    // Sentinel-prefill states: one-hop data-poll handshake ground truth.
    (void)hipMemsetAsync(states, 0x7F, (size_t)SEQ * H * sizeof(float), stream);

    void* args[] = { (void*)&inputs, (void*)&W_in, (void*)&W_res, (void*)&states };
    (void)hipLaunchCooperativeKernel((void*)esn_scan, dim3(NBLK), dim3(NTHR),
                                     args, 0, stream);

    esn_out<<<dim3(SEQ / 16), dim3(NTHR), 0, stream>>>(inputs, W_out, states, outputs);
}

// Round 13
// 8404.153 us; speedup vs baseline: 1.6471x; 1.0045x over previous
//
#include <hip/hip_runtime.h>

#define H 4096
#define IN 64
#define OUTD 64
#define SEQ 4096
#define NBLK 256
#define ROWS_PER_BLK 16
#define NTHR 1024
#define SENT 0x7F7F7F7Fu   // 3.39e38f; tanh output in [-1,1] can never equal it

// ---- device-coherent (L2-bypassing, MALL-point) accessors -----------------
__device__ __forceinline__ uint4 cpoll1(const unsigned* p) {
    uint4 v;
    asm volatile("global_load_dwordx4 %0, %1, off sc0 sc1\n\t"
                 "s_waitcnt vmcnt(0)"
                 : "=&v"(v) : "v"(p) : "memory");
    return v;
}
__device__ __forceinline__ void coherent_store_f32(float* p, float v) {
    asm volatile("global_store_dword %0, %1, off sc0 sc1"
                 :: "v"(p), "v"(v) : "memory");
}

__device__ __forceinline__ float row16_allreduce(float x) {
    x += __int_as_float(__builtin_amdgcn_update_dpp(0, __float_as_int(x), 0x128, 0xf, 0xf, false)); // row_ror:8
    x += __int_as_float(__builtin_amdgcn_update_dpp(0, __float_as_int(x), 0x124, 0xf, 0xf, false)); // row_ror:4
    x += __int_as_float(__builtin_amdgcn_update_dpp(0, __float_as_int(x), 0x122, 0xf, 0xf, false)); // row_ror:2
    x += __int_as_float(__builtin_amdgcn_update_dpp(0, __float_as_int(x), 0x121, 0xf, 0xf, false)); // row_ror:1
    return x;
}
__device__ __forceinline__ float quad4_allreduce(float x) {
    x += __int_as_float(__builtin_amdgcn_update_dpp(0, __float_as_int(x), 0xB1, 0xf, 0xf, false)); // perm 1,0,3,2
    x += __int_as_float(__builtin_amdgcn_update_dpp(0, __float_as_int(x), 0x4E, 0xf, 0xf, false)); // perm 2,3,0,1
    return x;
}

__global__ __launch_bounds__(NTHR, 4)
void esn_scan(const float* __restrict__ inputs,   // (SEQ, IN)
              const float* __restrict__ W_in,     // (H, IN)
              const float* __restrict__ W_res,    // (H, H)
              float* __restrict__ out_states)     // (SEQ, H), sentinel-prefilled
{
    __shared__ alignas(16) float4 s_state4[H / 4];        // 1024 swizzled quads
    __shared__ alignas(16) float s_win[ROWS_PER_BLK][65]; // padded
    __shared__ alignas(16) float s_part[2][16][20];       // [parity][k(wave)][row+pad]
    __shared__ alignas(16) float s_u[IN];                 // wave0-local

    const int tid  = threadIdx.x;
    const int row0 = blockIdx.x * ROWS_PER_BLK;
    const int wave = tid >> 6;
    const int lane = tid & 63;
    const int rg   = lane >> 4;   // 0..3
    const int cgi  = lane & 15;   // 0..15
    const int col0 = wave * 256 + cgi * 16;

    // staging: thread polls ONE 16B quad: producer sp = tid>>2, sub-quad sq = tid&3
    // LDS slot = 64*(sp>>4) + 16*sq + (sp&15)  == wave-local region [64w, 64w+64)
    const int sp    = tid >> 2;
    const int sq    = tid & 3;
    const int sslot = 64 * (sp >> 4) + 16 * sq + (sp & 15);
    const int scol  = sp * 16 + sq * 4;

    for (int idx = tid; idx < ROWS_PER_BLK * IN; idx += NTHR)
        s_win[idx >> 6][idx & 63] = W_in[(size_t)row0 * IN + idx];

    float w[4][16];
#pragma unroll
    for (int j = 0; j < 4; ++j) {
        const float* src = W_res + (size_t)(row0 + 4 * rg + j) * H + col0;
#pragma unroll
        for (int q = 0; q < 4; ++q) {
            float4 v = *(const float4*)(src + 4 * q);
            w[j][4 * q + 0] = v.x; w[j][4 * q + 1] = v.y;
            w[j][4 * q + 2] = v.z; w[j][4 * q + 3] = v.w;
        }
    }
    __syncthreads();   // s_win visible to wave0 before first phase-3

    for (int t = 0; t < SEQ; ++t) {
        const int par = t & 1;
        // ---- stage u_t (wave0-local; program-order safe vs phase-3 reads)
        if (tid < 16)
            ((float4*)s_u)[tid] = ((const float4*)(inputs + (size_t)t * IN))[tid];
        // ---- stage state row t-1: one-hop 16B poll with calibrated backoff.
        // NO B1: staging/readback strictly wave-local; each wave starts FMA as
        // soon as ITS producers land (compute overlaps producer skew). Poll
        // traffic is throttled by the backoff (R12), so freed waves don't
        // saturate the fabric (the R6 failure mode).
        if (t == 0) {
            s_state4[sslot] = make_float4(0.f, 0.f, 0.f, 0.f);
        } else {
            const unsigned* p =
                (const unsigned*)(out_states + (size_t)(t - 1) * H + scol);
            uint4 v = cpoll1(p);
            if ((v.x == SENT) | (v.y == SENT) | (v.z == SENT) | (v.w == SENT)) {
                __builtin_amdgcn_s_sleep(8);   // skip publish dead-window
                for (;;) {
                    v = cpoll1(p);
                    if ((v.x != SENT) & (v.y != SENT) &
                        (v.z != SENT) & (v.w != SENT))
                        break;
                    __builtin_amdgcn_s_sleep(2);
                }
            }
            float4 f;
            f.x = __uint_as_float(v.x); f.y = __uint_as_float(v.y);
            f.z = __uint_as_float(v.z); f.w = __uint_as_float(v.w);
            s_state4[sslot] = f;
        }

        // ---- phase 2: 4 rows x 16 cols of FMA per lane, weights in VGPRs
        float a0 = 0.f, a1 = 0.f, a2 = 0.f, a3 = 0.f;
#pragma unroll
        for (int q = 0; q < 4; ++q) {
            float4 sv = s_state4[wave * 64 + q * 16 + cgi];
            a0 = fmaf(w[0][4*q+0], sv.x, a0); a0 = fmaf(w[0][4*q+1], sv.y, a0);
            a0 = fmaf(w[0][4*q+2], sv.z, a0); a0 = fmaf(w[0][4*q+3], sv.w, a0);
            a1 = fmaf(w[1][4*q+0], sv.x, a1); a1 = fmaf(w[1][4*q+1], sv.y, a1);
            a1 = fmaf(w[1][4*q+2], sv.z, a1); a1 = fmaf(w[1][4*q+3], sv.w, a1);
            a2 = fmaf(w[2][4*q+0], sv.x, a2); a2 = fmaf(w[2][4*q+1], sv.y, a2);
            a2 = fmaf(w[2][4*q+2], sv.z, a2); a2 = fmaf(w[2][4*q+3], sv.w, a2);
            a3 = fmaf(w[3][4*q+0], sv.x, a3); a3 = fmaf(w[3][4*q+1], sv.y, a3);
            a3 = fmaf(w[3][4*q+2], sv.z, a3); a3 = fmaf(w[3][4*q+3], sv.w, a3);
        }
        a0 = row16_allreduce(a0);
        a1 = row16_allreduce(a1);
        a2 = row16_allreduce(a2);
        a3 = row16_allreduce(a3);
        if (cgi == 0) {
            float4 pv; pv.x = a0; pv.y = a1; pv.z = a2; pv.w = a3;
            *(float4*)&s_part[par][wave][4 * rg] = pv;
        }
        __syncthreads();   // B2: the only barrier per step

        // ---- phase 3: wave0 alone finishes all 16 rows; ONE coalesced 64B
        // publish. Waves 1..15 fall straight through to next step's polls.
        if (wave == 0) {
            const int row = lane >> 2;  // 0..15
            const int j   = lane & 3;   // partial group
            float v = s_part[par][4*j+0][row] + s_part[par][4*j+1][row]
                    + s_part[par][4*j+2][row] + s_part[par][4*j+3][row];
#pragma unroll
            for (int e = 0; e < 16; ++e)
                v = fmaf(s_win[row][16*j + e], s_u[16*j + e], v);
            v = quad4_allreduce(v);
            if (j == 0)
                coherent_store_f32(&out_states[(size_t)t * H + row0 + row],
                                   tanhf(v));
        }
        // s_part reuse protected by parity + B2 ordering (see analysis).
    }
}

__device__ __forceinline__ float wave64_allreduce(float x) {
#pragma unroll
    for (int m = 1; m < 64; m <<= 1) x += __shfl_xor(x, m, 64);
    return x;
}

// One wave per timestep s; states row cached in 16 float4 regs across all 64 o.
__global__ __launch_bounds__(NTHR)
void esn_out(const float* __restrict__ inputs,
             const float* __restrict__ W_out,    // (OUTD, 4161) row-major
             const float* __restrict__ states,   // (SEQ, H)
             float* __restrict__ outputs)        // (SEQ, OUTD)
{
    const int wv   = threadIdx.x >> 6;
    const int lane = threadIdx.x & 63;
    const int s    = blockIdx.x * 16 + wv;
    const int K    = 1 + IN + H; // 4161

    const float4* st4 = (const float4*)(states + (size_t)s * H);
    float4 sq[16];
#pragma unroll
    for (int k = 0; k < 16; ++k)
        sq[k] = st4[64 * k + lane];
    float4 iq = make_float4(0.f, 0.f, 0.f, 0.f);
    if (lane < 16)
        iq = ((const float4*)(inputs + (size_t)s * IN))[lane];

    for (int o = 0; o < OUTD; ++o) {
        const float* wrow = W_out + (size_t)o * K;
        float acc = 0.f;
#pragma unroll
        for (int k = 0; k < 16; ++k) {
            float4 wq;   // wrow+65 is only 4B-aligned -> memcpy (dword loads)
            __builtin_memcpy(&wq, wrow + 65 + 4 * (64 * k + lane), 16);
            acc = fmaf(wq.x, sq[k].x, acc);
            acc = fmaf(wq.y, sq[k].y, acc);
            acc = fmaf(wq.z, sq[k].z, acc);
            acc = fmaf(wq.w, sq[k].w, acc);
        }
        if (lane < 16) {
            float4 wi;
            __builtin_memcpy(&wi, wrow + 1 + 4 * lane, 16);
            acc = fmaf(wi.x, iq.x, acc);
            acc = fmaf(wi.y, iq.y, acc);
            acc = fmaf(wi.z, iq.z, acc);
            acc = fmaf(wi.w, iq.w, acc);
            if (lane == 0) acc += wrow[0];   // bias
        }
        acc = wave64_allreduce(acc);
        if (lane == 0) outputs[(size_t)s * OUTD + o] = acc;
    }
}

extern "C" void kernel_launch(void* const* d_in, const int* in_sizes, int n_in,
                              void* d_out, int out_size, void* d_ws, size_t ws_size,
                              hipStream_t stream) {
    const float* inputs = (const float*)d_in[0];
    const float* W_in   = (const float*)d_in[1];
    const float* W_res  = (const float*)d_in[2];
    const float* W_out  = (const float*)d_in[3];

    float* outputs = (float*)d_out;                        // (SEQ, OUTD)
    float* states  = (float*)d_out + (size_t)SEQ * OUTD;   // (SEQ, H)

    // Sentinel-prefill states: one-hop data-poll handshake ground truth.
    (void)hipMemsetAsync(states, 0x7F, (size_t)SEQ * H * sizeof(float), stream);

    void* args[] = { (void*)&inputs, (void*)&W_in, (void*)&W_res, (void*)&states };
    (void)hipLaunchCooperativeKernel((void*)esn_scan, dim3(NBLK), dim3(NTHR),
                                     args, 0, stream);

    esn_out<<<dim3(SEQ / 16), dim3(NTHR), 0, stream>>>(inputs, W_out, states, outputs);
}